// Round 1
// baseline (1774.622 us; speedup 1.0000x reference)
//
#include <hip/hip_runtime.h>
#include <hip/hip_bf16.h>
#include <stdint.h>

typedef __bf16 bf16_t;
typedef __bf16 bf16x8 __attribute__((ext_vector_type(8)));
typedef float f32x4 __attribute__((ext_vector_type(4)));

__device__ __forceinline__ bf16x8 ldb8(const bf16_t* p) {
    return *reinterpret_cast<const bf16x8*>(p);
}

__global__ __launch_bounds__(256) void zerof(float* __restrict__ p, int n) {
    int i = blockIdx.x * 256 + threadIdx.x;
    if (i < n) p[i] = 0.f;
}

// fp32 -> (bf16 hi, bf16 lo) split; hi+lo reproduces fp32 to ~2^-17 rel.
__global__ __launch_bounds__(256) void split_k(const float* __restrict__ in,
                                               bf16_t* __restrict__ hi,
                                               bf16_t* __restrict__ lo, long n) {
    long i = (long)blockIdx.x * 256 + threadIdx.x;
    if (i >= n) return;
    float v = in[i];
    bf16_t h = (bf16_t)v;
    hi[i] = h;
    lo[i] = (bf16_t)(v - (float)h);
}

// w [27][Cin][Cout] fp32 -> wt [27][Cout][Cin] bf16 hi/lo (B-fragment friendly:
// 8 consecutive Cin elems per MFMA fragment = one 16B load). Write-coalesced.
__global__ __launch_bounds__(256) void wtrans(const float* __restrict__ w,
                                              bf16_t* __restrict__ hi,
                                              bf16_t* __restrict__ lo,
                                              int Cin, int Cout) {
    long i = (long)blockIdx.x * 256 + threadIdx.x;
    long total = 27L * Cin * Cout;
    if (i >= total) return;
    int ci = (int)(i % Cin);
    long t = i / Cin;
    int co = (int)(t % Cout);
    int k  = (int)(t / Cout);
    float v = w[((long)k * Cin + ci) * Cout + co];
    bf16_t h = (bf16_t)v;
    hi[i] = h;
    lo[i] = (bf16_t)(v - (float)h);
}

// Gather-GEMM: out[m, :] = sum_k feat[nb[k][m], :] @ w[k]  (fp32 accum via MFMA)
// Block: 256 thr = 4 waves; wave handles 32 rows (2 tiles of 16) x COUT cols.
// 3-term split-bf16: hiA*hiB + hiA*loB + loA*hiB.
template <int CIN, int COUT>
__global__ __launch_bounds__(256) void conv_mfma(
    const bf16_t* __restrict__ fhi, const bf16_t* __restrict__ flo,
    const int* __restrict__ nb,
    const bf16_t* __restrict__ whi, const bf16_t* __restrict__ wlo,
    const bf16_t* __restrict__ zrow,
    float* __restrict__ out, int M) {
    constexpr int CT = COUT / 16;
    constexpr int KT = CIN / 32;
    const int lane = threadIdx.x & 63;
    const int wave = threadIdx.x >> 6;
    const int quad = lane >> 4;
    const int r16  = lane & 15;
    const int row0 = blockIdx.x * 128 + wave * 32 + r16;  // A-operand row (lane&15)
    const int row1 = row0 + 16;

    f32x4 zacc = {0.f, 0.f, 0.f, 0.f};
    f32x4 acc[2][CT];
#pragma unroll
    for (int t = 0; t < 2; t++)
#pragma unroll
        for (int c = 0; c < CT; c++) acc[t][c] = zacc;

    for (int k = 0; k < 27; k++) {
        const int idx0 = nb[(long)k * M + row0];
        const int idx1 = nb[(long)k * M + row1];
        if (__ballot((idx0 >= 0) || (idx1 >= 0)) == 0ull) continue;  // plane-structured skip
        const bf16_t* a0h = (idx0 >= 0 ? fhi + (long)idx0 * CIN : zrow) + quad * 8;
        const bf16_t* a0l = (idx0 >= 0 ? flo + (long)idx0 * CIN : zrow) + quad * 8;
        const bf16_t* a1h = (idx1 >= 0 ? fhi + (long)idx1 * CIN : zrow) + quad * 8;
        const bf16_t* a1l = (idx1 >= 0 ? flo + (long)idx1 * CIN : zrow) + quad * 8;
        const bf16_t* wh = whi + (long)k * COUT * CIN + (long)r16 * CIN + quad * 8;
        const bf16_t* wl = wlo + (long)k * COUT * CIN + (long)r16 * CIN + quad * 8;
#pragma unroll
        for (int kk = 0; kk < KT; kk++) {
            bf16x8 A0H = ldb8(a0h + kk * 32);
            bf16x8 A0L = ldb8(a0l + kk * 32);
            bf16x8 A1H = ldb8(a1h + kk * 32);
            bf16x8 A1L = ldb8(a1l + kk * 32);
#pragma unroll
            for (int c = 0; c < CT; c++) {
                bf16x8 BH = ldb8(wh + (long)c * 16 * CIN + kk * 32);
                bf16x8 BL = ldb8(wl + (long)c * 16 * CIN + kk * 32);
                acc[0][c] = __builtin_amdgcn_mfma_f32_16x16x32_bf16(A0H, BH, acc[0][c], 0, 0, 0);
                acc[0][c] = __builtin_amdgcn_mfma_f32_16x16x32_bf16(A0H, BL, acc[0][c], 0, 0, 0);
                acc[0][c] = __builtin_amdgcn_mfma_f32_16x16x32_bf16(A0L, BH, acc[0][c], 0, 0, 0);
                acc[1][c] = __builtin_amdgcn_mfma_f32_16x16x32_bf16(A1H, BH, acc[1][c], 0, 0, 0);
                acc[1][c] = __builtin_amdgcn_mfma_f32_16x16x32_bf16(A1H, BL, acc[1][c], 0, 0, 0);
                acc[1][c] = __builtin_amdgcn_mfma_f32_16x16x32_bf16(A1L, BH, acc[1][c], 0, 0, 0);
            }
        }
    }
    // D layout: row = quad*4 + reg, col = lane&15 (m89/m91-verified)
    const int ob = blockIdx.x * 128 + wave * 32 + quad * 4;
#pragma unroll
    for (int t = 0; t < 2; t++)
#pragma unroll
        for (int c = 0; c < CT; c++)
#pragma unroll
            for (int r = 0; r < 4; r++)
                out[(long)(ob + t * 16 + r) * COUT + c * 16 + r16] = acc[t][c][r];
}

// Per-channel sum & sumsq over rows -> sums[0..C-1]=sum, sums[C..2C-1]=sumsq
__global__ __launch_bounds__(256) void bn_stats(const float* __restrict__ f, int M, int C,
                                                float* __restrict__ sums) {
    const int tid = threadIdx.x;
    const int col = tid & (C - 1);  // C in {128, 32}
    const int sub = tid / C;
    const int R = 256 / C;
    long rEnd = (long)(blockIdx.x + 1) * 256;
    if (rEnd > M) rEnd = M;
    float s = 0.f, s2 = 0.f;
    for (long r = (long)blockIdx.x * 256 + sub; r < rEnd; r += R) {
        float v = f[r * C + col];
        s += v;
        s2 = fmaf(v, v, s2);
    }
    __shared__ float l1[256], l2[256];
    l1[tid] = s;
    l2[tid] = s2;
    __syncthreads();
    if (sub == 0) {
        for (int i = 1; i < R; i++) { s += l1[col + i * C]; s2 += l2[col + i * C]; }
        atomicAdd(&sums[col], s);
        atomicAdd(&sums[C + col], s2);
    }
}

// BN(train) + optional residual + ReLU; writes bf16 hi/lo feature (or final fp32)
__global__ __launch_bounds__(256) void bn_apply(
    const float* __restrict__ f, const float* __restrict__ sums,
    const float* __restrict__ g, const float* __restrict__ bta,
    const bf16_t* __restrict__ idnh, const bf16_t* __restrict__ idnl,
    bf16_t* __restrict__ outh, bf16_t* __restrict__ outl,
    float* __restrict__ outf, long total, int C, float invM) {
    long i = (long)blockIdx.x * 256 + threadIdx.x;
    if (i >= total) return;
    int col = (int)(i & (C - 1));
    float mu = sums[col] * invM;
    float var = sums[C + col] * invM - mu * mu;
    if (var < 0.f) var = 0.f;
    float sc = g[col] * rsqrtf(var + 1e-5f);
    float v = (f[i] - mu) * sc + bta[col];
    if (idnh) v += (float)idnh[i] + (float)idnl[i];
    v = fmaxf(v, 0.f);
    if (outf) {
        outf[i] = v;
    } else {
        bf16_t h = (bf16_t)v;
        outh[i] = h;
        outl[i] = (bf16_t)(v - (float)h);
    }
}

extern "C" void kernel_launch(void* const* d_in, const int* in_sizes, int n_in,
                              void* d_out, int out_size, void* d_ws, size_t ws_size,
                              hipStream_t stream) {
    (void)n_in; (void)out_size; (void)ws_size;
    const float* x    = (const float*)d_in[0];
    const float* w_s1 = (const float*)d_in[1];
    const float* g_s1 = (const float*)d_in[2];
    const float* b_s1 = (const float*)d_in[3];
    const float* w11  = (const float*)d_in[4];
    const float* g11  = (const float*)d_in[5];
    const float* b11  = (const float*)d_in[6];
    const float* w12  = (const float*)d_in[7];
    const float* g12  = (const float*)d_in[8];
    const float* b12  = (const float*)d_in[9];
    const float* w21  = (const float*)d_in[10];
    const float* g21  = (const float*)d_in[11];
    const float* b21  = (const float*)d_in[12];
    const float* w22  = (const float*)d_in[13];
    const float* g22  = (const float*)d_in[14];
    const float* b22  = (const float*)d_in[15];
    const float* w_s2 = (const float*)d_in[16];
    const float* g_s2 = (const float*)d_in[17];
    const float* b_s2 = (const float*)d_in[18];
    const int* nb1 = (const int*)d_in[19];
    const int* nbs = (const int*)d_in[20];
    const int* nb2 = (const int*)d_in[21];

    const int N0 = in_sizes[0] / 256;   // 9216
    const int M1 = in_sizes[19] / 27;   // 27648
    const int M2 = in_sizes[21] / 27;   // 46080

    char* base = (char*)d_ws;
    size_t off = 0;
    auto alloc = [&](size_t bytes) -> char* {
        off = (off + 255) & ~(size_t)255;
        char* p = base + off;
        off += bytes;
        return p;
    };
    bf16_t* xh   = (bf16_t*)alloc((size_t)N0 * 256 * 2);
    bf16_t* xl   = (bf16_t*)alloc((size_t)N0 * 256 * 2);
    bf16_t* w1h  = (bf16_t*)alloc(27UL * 128 * 256 * 2);
    bf16_t* w1l  = (bf16_t*)alloc(27UL * 128 * 256 * 2);
    bf16_t* w11h = (bf16_t*)alloc(27UL * 128 * 128 * 2);
    bf16_t* w11l = (bf16_t*)alloc(27UL * 128 * 128 * 2);
    bf16_t* w12h = (bf16_t*)alloc(27UL * 128 * 128 * 2);
    bf16_t* w12l = (bf16_t*)alloc(27UL * 128 * 128 * 2);
    bf16_t* w21h = (bf16_t*)alloc(27UL * 128 * 128 * 2);
    bf16_t* w21l = (bf16_t*)alloc(27UL * 128 * 128 * 2);
    bf16_t* w22h = (bf16_t*)alloc(27UL * 128 * 128 * 2);
    bf16_t* w22l = (bf16_t*)alloc(27UL * 128 * 128 * 2);
    bf16_t* w2h  = (bf16_t*)alloc(27UL * 32 * 128 * 2);
    bf16_t* w2l  = (bf16_t*)alloc(27UL * 32 * 128 * 2);
    bf16_t* fAh  = (bf16_t*)alloc((size_t)M1 * 128 * 2);
    bf16_t* fAl  = (bf16_t*)alloc((size_t)M1 * 128 * 2);
    bf16_t* fBh  = (bf16_t*)alloc((size_t)M1 * 128 * 2);
    bf16_t* fBl  = (bf16_t*)alloc((size_t)M1 * 128 * 2);
    float*  cbuf = (float*)alloc((size_t)M1 * 128 * 4);   // also covers M2*32
    float*  stats = (float*)alloc(6UL * 256 * 4);         // 6 layers x 2*C
    bf16_t* zrow  = (bf16_t*)alloc(256 * 2);              // zero row for invalid taps

    // stats (6144 B) + zrow (512 B) are contiguous: zero both (ws is poisoned 0xAA)
    zerof<<<7, 256, 0, stream>>>(stats, 1664);

    long nx = (long)N0 * 256;
    split_k<<<(int)((nx + 255) / 256), 256, 0, stream>>>(x, xh, xl, nx);
    wtrans<<<(27 * 256 * 128 + 255) / 256, 256, 0, stream>>>(w_s1, w1h, w1l, 256, 128);
    wtrans<<<(27 * 128 * 128 + 255) / 256, 256, 0, stream>>>(w11, w11h, w11l, 128, 128);
    wtrans<<<(27 * 128 * 128 + 255) / 256, 256, 0, stream>>>(w12, w12h, w12l, 128, 128);
    wtrans<<<(27 * 128 * 128 + 255) / 256, 256, 0, stream>>>(w21, w21h, w21l, 128, 128);
    wtrans<<<(27 * 128 * 128 + 255) / 256, 256, 0, stream>>>(w22, w22h, w22l, 128, 128);
    wtrans<<<(27 * 128 * 32 + 255) / 256, 256, 0, stream>>>(w_s2, w2h, w2l, 128, 32);

    const float inv1 = 1.f / (float)M1, inv2 = 1.f / (float)M2;
    const int gconv1 = M1 / 128;                 // 216
    const int gstat1 = (M1 + 255) / 256;
    const long e1 = (long)M1 * 128;
    const int gapp1 = (int)((e1 + 255) / 256);

    // L1: spconv1 (256 -> 128)
    conv_mfma<256, 128><<<gconv1, 256, 0, stream>>>(xh, xl, nb1, w1h, w1l, zrow, cbuf, M1);
    bn_stats<<<gstat1, 256, 0, stream>>>(cbuf, M1, 128, stats);
    bn_apply<<<gapp1, 256, 0, stream>>>(cbuf, stats, g_s1, b_s1, nullptr, nullptr,
                                        fAh, fAl, nullptr, e1, 128, inv1);
    // Block 1
    conv_mfma<128, 128><<<gconv1, 256, 0, stream>>>(fAh, fAl, nbs, w11h, w11l, zrow, cbuf, M1);
    bn_stats<<<gstat1, 256, 0, stream>>>(cbuf, M1, 128, stats + 256);
    bn_apply<<<gapp1, 256, 0, stream>>>(cbuf, stats + 256, g11, b11, nullptr, nullptr,
                                        fBh, fBl, nullptr, e1, 128, inv1);
    conv_mfma<128, 128><<<gconv1, 256, 0, stream>>>(fBh, fBl, nbs, w12h, w12l, zrow, cbuf, M1);
    bn_stats<<<gstat1, 256, 0, stream>>>(cbuf, M1, 128, stats + 512);
    bn_apply<<<gapp1, 256, 0, stream>>>(cbuf, stats + 512, g12, b12, fAh, fAl,
                                        fAh, fAl, nullptr, e1, 128, inv1);
    // Block 2
    conv_mfma<128, 128><<<gconv1, 256, 0, stream>>>(fAh, fAl, nbs, w21h, w21l, zrow, cbuf, M1);
    bn_stats<<<gstat1, 256, 0, stream>>>(cbuf, M1, 128, stats + 768);
    bn_apply<<<gapp1, 256, 0, stream>>>(cbuf, stats + 768, g21, b21, nullptr, nullptr,
                                        fBh, fBl, nullptr, e1, 128, inv1);
    conv_mfma<128, 128><<<gconv1, 256, 0, stream>>>(fBh, fBl, nbs, w22h, w22l, zrow, cbuf, M1);
    bn_stats<<<gstat1, 256, 0, stream>>>(cbuf, M1, 128, stats + 1024);
    bn_apply<<<gapp1, 256, 0, stream>>>(cbuf, stats + 1024, g22, b22, fAh, fAl,
                                        fAh, fAl, nullptr, e1, 128, inv1);
    // L6: spconv2 (128 -> 32), final output fp32
    conv_mfma<128, 32><<<M2 / 128, 256, 0, stream>>>(fAh, fAl, nb2, w2h, w2l, zrow, cbuf, M2);
    bn_stats<<<(M2 + 255) / 256, 256, 0, stream>>>(cbuf, M2, 32, stats + 1280);
    const long e2 = (long)M2 * 32;
    bn_apply<<<(int)((e2 + 255) / 256), 256, 0, stream>>>(cbuf, stats + 1280, g_s2, b_s2,
                                                          nullptr, nullptr, nullptr, nullptr,
                                                          (float*)d_out, e2, 32, inv2);
}